// Round 1
// baseline (12469.083 us; speedup 1.0000x reference)
//
#include <hip/hip_runtime.h>
#include <math.h>
#include <stdint.h>

// Problem constants
#define B_ROWS 512
#define H_UNITS 16384
#define K_IN 2048
#define K_SEL 64
#define QPT 16  // keys per thread = 16384 / 1024
#define CAND_CAP 4096

// ---------------------------------------------------------------------------
// Kernel 1: encoding = inputs @ W^T  (fp32 mul, 64-chunk fp32 acc, fp64 chunk sum)
// C[512][16384] = A[512][2048] . W[16384][2048]^T   -- C lives in d_out
// (unchanged from the PASSING version -- exactness-validated, do not touch)
// ---------------------------------------------------------------------------
__global__ __launch_bounds__(256) void gemm_kernel(const float* __restrict__ A,
                                                   const float* __restrict__ W,
                                                   float* __restrict__ C) {
  __shared__ __align__(16) float As[64][68];
  __shared__ __align__(16) float Bs[64][68];
  const int tid = threadIdx.x;
  const int tx = tid & 15, ty = tid >> 4;
  const int bm = blockIdx.y * 64, bn = blockIdx.x * 64;

  double accd[16];
#pragma unroll
  for (int i = 0; i < 16; ++i) accd[i] = 0.0;

  const float* Ab = A + (size_t)bm * K_IN;
  const float* Wb = W + (size_t)bn * K_IN;

  for (int k0 = 0; k0 < K_IN; k0 += 64) {
#pragma unroll
    for (int p = 0; p < 4; ++p) {
      int id = p * 256 + tid;
      int m = id >> 4;
      int kq = (id & 15) << 2;
      float4 a = *reinterpret_cast<const float4*>(Ab + (size_t)m * K_IN + k0 + kq);
      As[kq + 0][m] = a.x; As[kq + 1][m] = a.y; As[kq + 2][m] = a.z; As[kq + 3][m] = a.w;
      float4 b = *reinterpret_cast<const float4*>(Wb + (size_t)m * K_IN + k0 + kq);
      Bs[kq + 0][m] = b.x; Bs[kq + 1][m] = b.y; Bs[kq + 2][m] = b.z; Bs[kq + 3][m] = b.w;
    }
    __syncthreads();

    float accf[16];
#pragma unroll
    for (int i = 0; i < 16; ++i) accf[i] = 0.0f;

#pragma unroll 16
    for (int kk = 0; kk < 64; ++kk) {
      float4 av = *reinterpret_cast<const float4*>(&As[kk][ty << 2]);
      float4 bv = *reinterpret_cast<const float4*>(&Bs[kk][tx << 2]);
      accf[0]  += av.x * bv.x; accf[1]  += av.x * bv.y; accf[2]  += av.x * bv.z; accf[3]  += av.x * bv.w;
      accf[4]  += av.y * bv.x; accf[5]  += av.y * bv.y; accf[6]  += av.y * bv.z; accf[7]  += av.y * bv.w;
      accf[8]  += av.z * bv.x; accf[9]  += av.z * bv.y; accf[10] += av.z * bv.z; accf[11] += av.z * bv.w;
      accf[12] += av.w * bv.x; accf[13] += av.w * bv.y; accf[14] += av.w * bv.z; accf[15] += av.w * bv.w;
    }
#pragma unroll
    for (int i = 0; i < 16; ++i) accd[i] += (double)accf[i];
    __syncthreads();
  }

#pragma unroll
  for (int i = 0; i < 4; ++i) {
    size_t rowoff = (size_t)(bm + (ty << 2) + i) * H_UNITS + bn + (tx << 2);
    float4 o;
    o.x = (float)accd[i * 4 + 0]; o.y = (float)accd[i * 4 + 1];
    o.z = (float)accd[i * 4 + 2]; o.w = (float)accd[i * 4 + 3];
    *reinterpret_cast<float4*>(C + rowoff) = o;
  }
}

// ---------------------------------------------------------------------------
// XLA float total order as u32: monotone bitcast (sign-magnitude flip).
// ---------------------------------------------------------------------------
__device__ __forceinline__ unsigned int orderable(float x) {
  unsigned int u = __float_as_uint(x);
  return u ^ ((u & 0x80000000u) ? 0xFFFFFFFFu : 0x80000000u);
}

// key for the (validated) final_brute tournament: (total order desc, idx asc)
__device__ __forceinline__ unsigned long long make_key(float r, int j) {
  unsigned int u = orderable(r);
  return (((unsigned long long)u) << 14) | (unsigned long long)(16383 - j);
}

// ---------------------------------------------------------------------------
// Old serial suffix_find -- kept verbatim for the (never-expected) slow path.
// ---------------------------------------------------------------------------
__device__ __forceinline__ void suffix_find(const unsigned int* hist, int CH, int need,
                                            int tid, int* s_b, int* s_above) {
  if (tid < 64) {
    unsigned int s = 0;
    for (int q = 0; q < CH; ++q) s += hist[tid * CH + q];
#pragma unroll
    for (int d = 1; d < 64; d <<= 1) {
      unsigned int o = __shfl_down(s, d);
      if (tid + d < 64) s += o;
    }
    unsigned int snext = __shfl_down(s, 1);
    if (tid == 63) snext = 0;
    bool cross = (s >= (unsigned int)need) && (snext < (unsigned int)need);
    unsigned long long bal = __ballot(cross);
    int g = __ffsll(bal) - 1;
    if (tid == g) {
      unsigned int acc = snext;
      int b = g * CH;
      for (int q = CH - 1; q >= 0; --q) {
        unsigned int c = hist[g * CH + q];
        if (acc + c >= (unsigned int)need) { b = g * CH + q; break; }
        acc += c;
      }
      *s_b = b; *s_above = (int)acc;
    }
  }
}

// ---------------------------------------------------------------------------
// Kernel 2 (REWRITTEN): sequential inhibition scan, 1 histogram pass +
// wave0 candidate-list refinement.
//   - pass1: 2048-bucket hist (top 11 bits), 2 replicas (wave parity),
//     XOR-swizzled addressing -> conflict-free suffix reads, spread atomics.
//   - wave0 finds threshold bucket b1 fully in-wave (no one-lane loops).
//   - all threads: bucket>b1 -> emit; bucket==b1 -> append (key<<14|~idx) to cand.
//   - wave0 alone refines the ~O(100) candidates 7 bits at a time,
//     wave-synchronously (no block barriers), emitting winners directly.
//     Ties at the exact 64th key resolve by smallest index via the packed key.
//   - 5 barriers/step (was 10); next row prefetched under pass1 atomics;
//     bmap double-buffered to drop the trailing barrier.
//   - exact same selection semantics as the validated 3-pass version.
// ---------------------------------------------------------------------------
__global__ __launch_bounds__(1024) void scan_radix(const float* __restrict__ enc,
                                                   int* __restrict__ seli) {
  const int tid = threadIdx.x;
  __shared__ unsigned int histA[2048];
  __shared__ unsigned int histB[2048];
  __shared__ unsigned int hist128[128];
  __shared__ unsigned int bmap[2][512];
  __shared__ unsigned long long cand[CAND_CAP];
  __shared__ int s_b1, s_nsel, s_ccnt, s_wtmp;
  __shared__ int s_b2, s_ab2, s_b3, s_ab3, s_tiecnt;

  float iv[QPT];
  float ec[QPT];
#pragma unroll
  for (int q = 0; q < QPT; ++q) iv[q] = 0.0f;
#pragma unroll
  for (int q = 0; q < QPT; ++q) ec[q] = enc[q * 1024 + tid];

  for (int t = 0; t < B_ROWS; ++t) {
    const int cur = t & 1;
    unsigned int* bm = bmap[cur];
    int* srow = seli + t * 64;

    // zero LDS (prev iter's readers of these are >=2 barriers back) + keys
    for (int i = tid; i < 2048; i += 1024) { histA[i] = 0u; histB[i] = 0u; }
    if (tid < 512) bm[tid] = 0u;
    if (tid == 0) { s_nsel = 0; s_ccnt = 0; }
    unsigned int ok[QPT];
#pragma unroll
    for (int q = 0; q < QPT; ++q) {
      float r = __fmul_rn(fabsf(ec[q]), __fsub_rn(1.0f, iv[q]));  // np-exact
      ok[q] = orderable(r);
    }
    __syncthreads();  // B1

    // prefetch next row (latency hides under pass1 atomics, drained at B2)
    const int tn = (t + 1 < B_ROWS) ? (t + 1) : t;
    const float* nrow = enc + (size_t)tn * H_UNITS;
    float en[QPT];
#pragma unroll
    for (int q = 0; q < QPT; ++q) en[q] = nrow[q * 1024 + tid];

    // pass 1: top 11 bits, 2 replicas, swizzled
    unsigned int* hrep = ((tid >> 6) & 1) ? histB : histA;
#pragma unroll
    for (int q = 0; q < QPT; ++q) {
      int b = (int)(ok[q] >> 21);
      int a = b ^ ((b >> 5) & 31);
      atomicAdd(&hrep[a], 1u);
    }
    __syncthreads();  // B2

    // wave0: find bucket b1 (fully in-wave, conflict-free reads)
    if (tid < 64) {
      unsigned int s = 0;
      const int base = tid << 5;
#pragma unroll
      for (int q = 0; q < 32; ++q) {
        int b = base + q;
        int a = b ^ ((b >> 5) & 31);
        s += histA[a] + histB[a];
      }
      unsigned int si = s;
#pragma unroll
      for (int d = 1; d < 64; d <<= 1) {
        unsigned int o = __shfl_down(si, d);
        if (tid + d < 64) si += o;
      }
      unsigned int snext = __shfl_down(si, 1);
      if (tid == 63) snext = 0u;
      bool cross = (si >= 64u) && (snext < 64u);
      unsigned long long bal = __ballot(cross);
      int g = __ffsll(bal) - 1;
      unsigned int sng = __shfl(snext, g);
      // refine within group g across lanes 0..31
      unsigned int c;
      {
        int b = (g << 5) + (tid & 31);
        int a = b ^ ((b >> 5) & 31);
        c = histA[a] + histB[a];
      }
      unsigned int ti2 = c;
#pragma unroll
      for (int d = 1; d < 32; d <<= 1) {
        unsigned int o = __shfl_down(ti2, d);
        if ((tid & 31) + d < 32) ti2 += o;
      }
      unsigned int incl = sng + ti2;               // S(g*32 + lane)
      unsigned int incln = __shfl_down(incl, 1);   // S(g*32 + lane + 1)
      if ((tid & 31) == 31) incln = sng;
      bool cr2 = (tid < 32) && (incl >= 64u) && (incln < 64u);
      unsigned long long bal2 = __ballot(cr2);
      int q2 = __ffsll(bal2) - 1;
      if (tid == q2) s_b1 = (g << 5) + q2;
    }
    __syncthreads();  // B3

    // collect: strictly-above buckets -> emit; threshold bucket -> candidates
    const unsigned int b1 = (unsigned int)s_b1;
#pragma unroll
    for (int q = 0; q < QPT; ++q) {
      unsigned int o = ok[q];
      unsigned int bb = o >> 21;
      if (bb >= b1) {
        int j = q * 1024 + tid;
        if (bb > b1) {
          int slot = atomicAdd(&s_nsel, 1);
          srow[slot] = j;
          atomicOr(&bm[j >> 5], 1u << (j & 31));
        } else {
          int p = atomicAdd(&s_ccnt, 1);
          if (p < CAND_CAP)
            cand[p] = (((unsigned long long)o) << 14) | (unsigned long long)(16383 - j);
        }
      }
    }
    __syncthreads();  // B4

    const int Cc0 = s_ccnt;
    if (Cc0 <= CAND_CAP) {
      // FAST PATH: wave0 alone finishes the selection among Cc0 candidates.
      if (tid < 64) {
        int needc = 64 - s_nsel;  // read before our own emits
        int Cc = Cc0;
        int shift = 28;  // 7-bit chunks over bits [34:0] of the packed key
        while (true) {
          if (Cc <= needc) {  // invariant Cc>=needc -> Cc==needc: take all
            for (int s = tid; s < Cc; s += 64) {
              unsigned long long k = cand[s];
              int j = 16383 - (int)(k & 0x3FFFull);
              int slot = atomicAdd(&s_nsel, 1);
              srow[slot] = j;
              atomicOr(&bm[j >> 5], 1u << (j & 31));
            }
            break;
          }
          hist128[tid] = 0u;
          hist128[tid + 64] = 0u;
          if (tid == 0) s_wtmp = 0;
          asm volatile("s_waitcnt lgkmcnt(0)" ::: "memory");
          for (int s = tid; s < Cc; s += 64) {
            int ch = (int)((cand[s] >> shift) & 127ull);
            atomicAdd(&hist128[ch], 1u);
          }
          asm volatile("s_waitcnt lgkmcnt(0)" ::: "memory");
          unsigned int c0 = hist128[2 * tid];
          unsigned int c1 = hist128[2 * tid + 1];
          unsigned int ps = c0 + c1;
#pragma unroll
          for (int d = 1; d < 64; d <<= 1) {
            unsigned int o = __shfl_down(ps, d);
            if (tid + d < 64) ps += o;
          }
          unsigned int incl = ps;                     // S(2*tid)
          unsigned int incln = __shfl_down(incl, 1);  // S(2*tid+2)
          if (tid == 63) incln = 0u;
          unsigned int smid = incl - c0;              // S(2*tid+1)
          bool crossHi = (smid >= (unsigned int)needc) && (incln < (unsigned int)needc);
          bool crossLo = (incl >= (unsigned int)needc) && (smid < (unsigned int)needc);
          unsigned long long bal = __ballot(crossHi || crossLo);
          int gl = __ffsll(bal) - 1;
          int hiF = __shfl((int)crossHi, gl);
          int vstar = 2 * gl + hiF;
          unsigned int aboveCh = (unsigned int)__shfl((int)(hiF ? incln : smid), gl);
          // emit chunk>vstar, compact chunk==vstar in place
          // (per-group reads precede writes; write pos < next group's reads)
          for (int s = tid; s < Cc; s += 64) {
            unsigned long long k = cand[s];
            int ch = (int)((k >> shift) & 127ull);
            if (ch > vstar) {
              int j = 16383 - (int)(k & 0x3FFFull);
              int slot = atomicAdd(&s_nsel, 1);
              srow[slot] = j;
              atomicOr(&bm[j >> 5], 1u << (j & 31));
            } else if (ch == vstar) {
              int p = atomicAdd(&s_wtmp, 1);
              cand[p] = k;
            }
          }
          asm volatile("s_waitcnt lgkmcnt(0)" ::: "memory");
          needc -= (int)aboveCh;   // aboveCh < needc always (strict crossing)
          Cc = s_wtmp;
          shift -= 7;
        }
      }
    } else {
      // SLOW PATH (candidate overflow -- never expected): proven 3-pass flow,
      // restricted to bucket b1 (above-bucket entries already emitted).
      int need2 = 64 - s_nsel;  // == above-bucket count, unmodified since B4
      for (int i = tid; i < 2048; i += 1024) histA[i] = 0u;
      if (tid < 1024) histB[tid] = 0u;
      if (tid == 0) s_tiecnt = 0;
      __syncthreads();
#pragma unroll
      for (int q = 0; q < QPT; ++q)
        if ((ok[q] >> 21) == b1) atomicAdd(&histA[(ok[q] >> 10) & 0x7FFu], 1u);
      __syncthreads();
      suffix_find(histA, 32, need2, tid, &s_b2, &s_ab2);
      __syncthreads();
      const unsigned int pfx = (b1 << 21) | ((unsigned int)s_b2 << 10);
      const int need3 = need2 - s_ab2;
#pragma unroll
      for (int q = 0; q < QPT; ++q)
        if ((ok[q] & 0xFFFFFC00u) == pfx) atomicAdd(&histB[ok[q] & 0x3FFu], 1u);
      __syncthreads();
      suffix_find(histB, 16, need3, tid, &s_b3, &s_ab3);
      __syncthreads();
      const unsigned int ostar = pfx | (unsigned int)s_b3;
      const int tneed = need3 - s_ab3;
      int* tl = (int*)cand;
#pragma unroll
      for (int q = 0; q < QPT; ++q) {
        unsigned int o = ok[q];
        int j = q * 1024 + tid;
        if (o > ostar && (o >> 21) == b1) {
          int slot = atomicAdd(&s_nsel, 1);
          srow[slot] = j;
          atomicOr(&bm[j >> 5], 1u << (j & 31));
        } else if (o == ostar) {
          int p = atomicAdd(&s_tiecnt, 1);
          if (p < 1024) tl[p] = j;
        }
      }
      __syncthreads();
      if (tid == 0) {
        int tc = s_tiecnt; if (tc > 1024) tc = 1024;
        for (int k = 0; k < tneed; ++k) {
          int bi = 0x7FFFFFFF, bpos = 0;
          for (int i = 0; i < tc; ++i) {
            int v = tl[i];
            if (v < bi) { bi = v; bpos = i; }
          }
          tl[bpos] = 0x7FFFFFFF;
          bm[bi >> 5] |= (1u << (bi & 31));
          srow[64 - tneed + k] = bi;
        }
      }
    }
    __syncthreads();  // B5: bmap complete before update; LDS safe for next zero

    // inhibition update in registers, np-exact; swap in prefetched row
#pragma unroll
    for (int q = 0; q < QPT; ++q) {
      int j = q * 1024 + tid;
      float m = ((bm[j >> 5] >> (j & 31)) & 1u) ? 1.0f : 0.0f;
      iv[q] = __fadd_rn(__fmul_rn(iv[q], 0.95f), m);
      ec[q] = en[q];
    }
  }
}

// ---------------------------------------------------------------------------
// Kernel 3: final top-64 over filtered = enc * mask, brute-force exact.
// (unchanged -- validated)
// ---------------------------------------------------------------------------
__global__ __launch_bounds__(1024) void final_brute(const int* __restrict__ seli,
                                                    float* __restrict__ out) {
  const int row = blockIdx.x;
  const int tid = threadIdx.x;
  __shared__ unsigned long long wmax[16];
  __shared__ unsigned long long s_win;
  __shared__ int wlist[64];
  __shared__ unsigned int bmap[512];
  const float* erow = out + (size_t)row * H_UNITS;

  if (tid < 512) bmap[tid] = 0u;
  __syncthreads();
  if (tid < 64) {
    int idx = seli[row * 64 + tid];
    atomicOr(&bmap[idx >> 5], 1u << (idx & 31));
  }
  __syncthreads();

  unsigned long long key[16];
  unsigned long long lmax = 0ull;
#pragma unroll
  for (int q = 0; q < 16; ++q) {
    int j = q * 1024 + tid;
    float e = erow[j];
    bool sel = (bmap[j >> 5] >> (j & 31)) & 1u;
    unsigned int eb = __float_as_uint(e);
    float f = __uint_as_float(sel ? eb : (eb & 0x80000000u));  // ±0 keeps sign
    unsigned long long k = make_key(f, j);
    key[q] = k;
    if (k > lmax) lmax = k;
  }
  __syncthreads();

  float4 z = make_float4(0.0f, 0.0f, 0.0f, 0.0f);
  float4* o4 = reinterpret_cast<float4*>(out + (size_t)row * H_UNITS);
  for (int i = tid; i < H_UNITS / 4; i += 1024) o4[i] = z;
  __syncthreads();

  for (int round = 0; round < 64; ++round) {
    unsigned long long v = lmax;
#pragma unroll
    for (int d = 32; d >= 1; d >>= 1) {
      unsigned long long o = __shfl_down(v, d);
      if (o > v) v = o;
    }
    if ((tid & 63) == 0) wmax[tid >> 6] = v;
    __syncthreads();
    if (tid == 0) {
      unsigned long long m = wmax[0];
#pragma unroll
      for (int w = 1; w < 16; ++w)
        if (wmax[w] > m) m = wmax[w];
      s_win = m;
      wlist[round] = 16383 - (int)(m & 0x3FFFull);
    }
    __syncthreads();
    unsigned long long Wk = s_win;
    if (lmax == Wk) {
      unsigned long long nm = 0ull;
#pragma unroll
      for (int q = 0; q < 16; ++q) {
        unsigned long long k = key[q];
        if (k < Wk && k > nm) nm = k;
      }
      lmax = nm;
    }
  }
  __syncthreads();
  if (tid < 64) out[(size_t)row * H_UNITS + wlist[tid]] = 1.0f;
}

// ---------------------------------------------------------------------------
extern "C" void kernel_launch(void* const* d_in, const int* in_sizes, int n_in,
                              void* d_out, int out_size, void* d_ws, size_t ws_size,
                              hipStream_t stream) {
  const float* inputs = (const float*)d_in[0];   // [512][2048] fp32
  const float* W = (const float*)d_in[1];        // [16384][2048] fp32
  float* out = (float*)d_out;                    // [512][16384] fp32 -- also enc scratch
  char* ws = (char*)d_ws;

  int* seli = (int*)(ws);                        // 131,072 B

  float* enc = out;  // encoding scratch lives in d_out

  gemm_kernel<<<dim3(H_UNITS / 64, B_ROWS / 64), 256, 0, stream>>>(inputs, W, enc);
  scan_radix<<<1, 1024, 0, stream>>>(enc, seli);
  final_brute<<<B_ROWS, 1024, 0, stream>>>(seli, out);
}

// Round 2
// 4107.214 us; speedup vs baseline: 3.0359x; 3.0359x over previous
//
#include <hip/hip_runtime.h>
#include <math.h>
#include <stdint.h>

// Problem constants
#define B_ROWS 512
#define H_UNITS 16384
#define K_IN 2048
#define K_SEL 64
#define QPT 16  // keys per thread = 16384 / 1024
#define CAND_MAX 2048
#define SWZ(b) ((b) ^ (((b) >> 5) & 31))

// ---------------------------------------------------------------------------
// Kernel 1: encoding = inputs @ W^T  (fp32 mul, 64-chunk fp32 acc, fp64 chunk sum)
// (unchanged from the PASSING version -- exactness-validated, do not touch)
// ---------------------------------------------------------------------------
__global__ __launch_bounds__(256) void gemm_kernel(const float* __restrict__ A,
                                                   const float* __restrict__ W,
                                                   float* __restrict__ C) {
  __shared__ __align__(16) float As[64][68];
  __shared__ __align__(16) float Bs[64][68];
  const int tid = threadIdx.x;
  const int tx = tid & 15, ty = tid >> 4;
  const int bm = blockIdx.y * 64, bn = blockIdx.x * 64;

  double accd[16];
#pragma unroll
  for (int i = 0; i < 16; ++i) accd[i] = 0.0;

  const float* Ab = A + (size_t)bm * K_IN;
  const float* Wb = W + (size_t)bn * K_IN;

  for (int k0 = 0; k0 < K_IN; k0 += 64) {
#pragma unroll
    for (int p = 0; p < 4; ++p) {
      int id = p * 256 + tid;
      int m = id >> 4;
      int kq = (id & 15) << 2;
      float4 a = *reinterpret_cast<const float4*>(Ab + (size_t)m * K_IN + k0 + kq);
      As[kq + 0][m] = a.x; As[kq + 1][m] = a.y; As[kq + 2][m] = a.z; As[kq + 3][m] = a.w;
      float4 b = *reinterpret_cast<const float4*>(Wb + (size_t)m * K_IN + k0 + kq);
      Bs[kq + 0][m] = b.x; Bs[kq + 1][m] = b.y; Bs[kq + 2][m] = b.z; Bs[kq + 3][m] = b.w;
    }
    __syncthreads();

    float accf[16];
#pragma unroll
    for (int i = 0; i < 16; ++i) accf[i] = 0.0f;

#pragma unroll 16
    for (int kk = 0; kk < 64; ++kk) {
      float4 av = *reinterpret_cast<const float4*>(&As[kk][ty << 2]);
      float4 bv = *reinterpret_cast<const float4*>(&Bs[kk][tx << 2]);
      accf[0]  += av.x * bv.x; accf[1]  += av.x * bv.y; accf[2]  += av.x * bv.z; accf[3]  += av.x * bv.w;
      accf[4]  += av.y * bv.x; accf[5]  += av.y * bv.y; accf[6]  += av.y * bv.z; accf[7]  += av.y * bv.w;
      accf[8]  += av.z * bv.x; accf[9]  += av.z * bv.y; accf[10] += av.z * bv.z; accf[11] += av.z * bv.w;
      accf[12] += av.w * bv.x; accf[13] += av.w * bv.y; accf[14] += av.w * bv.z; accf[15] += av.w * bv.w;
    }
#pragma unroll
    for (int i = 0; i < 16; ++i) accd[i] += (double)accf[i];
    __syncthreads();
  }

#pragma unroll
  for (int i = 0; i < 4; ++i) {
    size_t rowoff = (size_t)(bm + (ty << 2) + i) * H_UNITS + bn + (tx << 2);
    float4 o;
    o.x = (float)accd[i * 4 + 0]; o.y = (float)accd[i * 4 + 1];
    o.z = (float)accd[i * 4 + 2]; o.w = (float)accd[i * 4 + 3];
    *reinterpret_cast<float4*>(C + rowoff) = o;
  }
}

// ---------------------------------------------------------------------------
// XLA float total order as u32: monotone bitcast (sign-magnitude flip).
// ---------------------------------------------------------------------------
__device__ __forceinline__ unsigned int orderable(float x) {
  unsigned int u = __float_as_uint(x);
  return u ^ ((u & 0x80000000u) ? 0xFFFFFFFFu : 0x80000000u);
}

__device__ __forceinline__ unsigned long long make_key(float r, int j) {
  unsigned int u = orderable(r);
  return (((unsigned long long)u) << 14) | (unsigned long long)(16383 - j);
}

// ---------------------------------------------------------------------------
// Serial suffix bucket find (validated) -- used by old kernel + slow3 paths.
// ---------------------------------------------------------------------------
__device__ __forceinline__ void suffix_find(const unsigned int* hist, int CH, int need,
                                            int tid, int* s_b, int* s_above) {
  if (tid < 64) {
    unsigned int s = 0;
    for (int q = 0; q < CH; ++q) s += hist[tid * CH + q];
#pragma unroll
    for (int d = 1; d < 64; d <<= 1) {
      unsigned int o = __shfl_down(s, d);
      if (tid + d < 64) s += o;
    }
    unsigned int snext = __shfl_down(s, 1);
    if (tid == 63) snext = 0;
    bool cross = (s >= (unsigned int)need) && (snext < (unsigned int)need);
    unsigned long long bal = __ballot(cross);
    int g = __ffsll(bal) - 1;
    if (tid == g) {
      unsigned int acc = snext;
      int b = g * CH;
      for (int q = CH - 1; q >= 0; --q) {
        unsigned int c = hist[g * CH + q];
        if (acc + c >= (unsigned int)need) { b = g * CH + q; break; }
        acc += c;
      }
      *s_b = b; *s_above = (int)acc;
    }
  }
}

// ---------------------------------------------------------------------------
// In-wave (tid<64) suffix find over 2048 swizzled buckets (2 replicas).
// Outputs bucket b* = max b with S(b) >= need, and above = S(b*+1).
// (validated machinery from round-1 kernel, extended with `above` output)
// ---------------------------------------------------------------------------
__device__ __forceinline__ void wave_find2048(const unsigned int* ha, const unsigned int* hb,
                                              unsigned int need, int tid,
                                              int* s_b, unsigned int* s_above) {
  unsigned int s = 0;
  const int base = tid << 5;
#pragma unroll
  for (int q = 0; q < 32; ++q) {
    int b = base + q;
    int a = SWZ(b);
    s += ha[a] + hb[a];
  }
  unsigned int si = s;
#pragma unroll
  for (int d = 1; d < 64; d <<= 1) {
    unsigned int o = __shfl_down(si, d);
    if (tid + d < 64) si += o;
  }
  unsigned int snext = __shfl_down(si, 1);
  if (tid == 63) snext = 0u;
  bool cross = (si >= need) && (snext < need);
  unsigned long long bal = __ballot(cross);
  int g = __ffsll(bal) - 1;
  unsigned int sng = __shfl(snext, g);
  unsigned int c;
  {
    int b = (g << 5) + (tid & 31);
    int a = SWZ(b);
    c = ha[a] + hb[a];
  }
  unsigned int ti2 = c;
#pragma unroll
  for (int d = 1; d < 32; d <<= 1) {
    unsigned int o = __shfl_down(ti2, d);
    if ((tid & 31) + d < 32) ti2 += o;
  }
  unsigned int incl = sng + ti2;
  unsigned int incln = __shfl_down(incl, 1);
  if ((tid & 31) == 31) incln = sng;
  bool cr2 = (tid < 32) && (incl >= need) && (incln < need);
  unsigned long long bal2 = __ballot(cr2);
  int q2 = __ffsll(bal2) - 1;
  if (tid == q2) { *s_b = (g << 5) + q2; *s_above = incln; }
}

// ---------------------------------------------------------------------------
// Wave0 chunk refinement over packed 46-bit keys in cand[0..Cc), taking the
// `needc` largest; emits (srow, selJ, selK). Validated logic from round-1.
// Executed by tid<64 only.
// ---------------------------------------------------------------------------
__device__ __forceinline__ void wave_refine(unsigned long long* cand, unsigned int* hist128,
                                            int Cc, int needc, int* srow, int* selJ,
                                            unsigned long long* selK, int* s_nsel, int* s_wtmp) {
  const int tid = threadIdx.x;
  int shift = 28;
  while (true) {
    if (Cc <= needc) {
      for (int s = tid; s < Cc; s += 64) {
        unsigned long long k = cand[s];
        int j = 16383 - (int)(k & 0x3FFFull);
        int slot = atomicAdd(s_nsel, 1);
        srow[slot] = j; selJ[slot] = j; selK[slot] = k;
      }
      break;
    }
    hist128[tid] = 0u;
    hist128[tid + 64] = 0u;
    if (tid == 0) *s_wtmp = 0;
    asm volatile("s_waitcnt lgkmcnt(0)" ::: "memory");
    for (int s = tid; s < Cc; s += 64) {
      int ch = (int)((cand[s] >> shift) & 127ull);
      atomicAdd(&hist128[ch], 1u);
    }
    asm volatile("s_waitcnt lgkmcnt(0)" ::: "memory");
    unsigned int c0 = hist128[2 * tid];
    unsigned int c1 = hist128[2 * tid + 1];
    unsigned int ps = c0 + c1;
#pragma unroll
    for (int d = 1; d < 64; d <<= 1) {
      unsigned int o = __shfl_down(ps, d);
      if (tid + d < 64) ps += o;
    }
    unsigned int incl = ps;
    unsigned int incln = __shfl_down(incl, 1);
    if (tid == 63) incln = 0u;
    unsigned int smid = incl - c0;
    bool crossHi = (smid >= (unsigned int)needc) && (incln < (unsigned int)needc);
    bool crossLo = (incl >= (unsigned int)needc) && (smid < (unsigned int)needc);
    unsigned long long bal = __ballot(crossHi || crossLo);
    int gl = __ffsll(bal) - 1;
    int hiF = __shfl((int)crossHi, gl);
    int vstar = 2 * gl + hiF;
    unsigned int aboveCh = (unsigned int)__shfl((int)(hiF ? incln : smid), gl);
    for (int s = tid; s < Cc; s += 64) {
      unsigned long long k = cand[s];
      int ch = (int)((k >> shift) & 127ull);
      if (ch > vstar) {
        int j = 16383 - (int)(k & 0x3FFFull);
        int slot = atomicAdd(s_nsel, 1);
        srow[slot] = j; selJ[slot] = j; selK[slot] = k;
      } else if (ch == vstar) {
        int p = atomicAdd(s_wtmp, 1);
        cand[p] = k;
      }
    }
    asm volatile("s_waitcnt lgkmcnt(0)" ::: "memory");
    needc -= (int)aboveCh;
    Cc = *s_wtmp;
    shift -= 7;
  }
}

// ---------------------------------------------------------------------------
// Kernel 1.5 (NEW): per-row candidate precompute, full-GPU parallel.
// For each row: find boundary_o (2-level radix over orderable(|e|)) such that
// count{o(|e|) >= boundary} is in [1024, ~2048]; collect records (e_bits<<32|j)
// for those units; hdr[2r]=count (may exceed CAND_MAX => row falls back),
// hdr[2r+1]=boundary. Since r = fl(|e|*fl(1-i)) <= |e| exactly (i>=0, monotone
// rounding), every excluded unit's key is < boundary<<14 forever.
// ---------------------------------------------------------------------------
__global__ __launch_bounds__(1024) void precomp_cand(const float* __restrict__ enc,
                                                     unsigned long long* __restrict__ rec,
                                                     unsigned int* __restrict__ hdr) {
  const int row = blockIdx.x;
  const int tid = threadIdx.x;
  __shared__ unsigned int hA[2048], hB[2048], h2a[2048], h2b[2048];
  __shared__ int s_b1; __shared__ unsigned int s_ab1;
  __shared__ int s_b2; __shared__ unsigned int s_ab2;
  __shared__ int s_cnt;
  const float* erow = enc + (size_t)row * H_UNITS;

  unsigned int ob[QPT], eb[QPT];
  for (int i = tid; i < 2048; i += 1024) { hA[i] = 0u; hB[i] = 0u; h2a[i] = 0u; h2b[i] = 0u; }
  if (tid == 0) s_cnt = 0;
#pragma unroll
  for (int q = 0; q < QPT; ++q) {
    int j = q * 1024 + tid;
    float e = erow[j];
    eb[q] = __float_as_uint(e);
    ob[q] = orderable(fabsf(e));
  }
  __syncthreads();

  unsigned int* hrep = ((tid >> 6) & 1) ? hB : hA;
#pragma unroll
  for (int q = 0; q < QPT; ++q) {
    int b = (int)(ob[q] >> 21);
    atomicAdd(&hrep[SWZ(b)], 1u);
  }
  __syncthreads();
  if (tid < 64) wave_find2048(hA, hB, 1024u, tid, &s_b1, &s_ab1);
  __syncthreads();

  const unsigned int b1 = (unsigned int)s_b1;
  const unsigned int need2 = 1024u - s_ab1;
  unsigned int* h2rep = ((tid >> 6) & 1) ? h2b : h2a;
#pragma unroll
  for (int q = 0; q < QPT; ++q) {
    if ((ob[q] >> 21) == b1) {
      int b = (int)((ob[q] >> 10) & 0x7FFu);
      atomicAdd(&h2rep[SWZ(b)], 1u);
    }
  }
  __syncthreads();
  if (tid < 64) wave_find2048(h2a, h2b, need2, tid, &s_b2, &s_ab2);
  __syncthreads();

  const unsigned int bnd = (b1 << 21) | ((unsigned int)s_b2 << 10);
#pragma unroll
  for (int q = 0; q < QPT; ++q) {
    if (ob[q] >= bnd) {
      int p = atomicAdd(&s_cnt, 1);
      if (p < CAND_MAX)
        rec[(size_t)row * CAND_MAX + p] =
            (((unsigned long long)eb[q]) << 32) | (unsigned long long)(q * 1024 + tid);
    }
  }
  __syncthreads();
  if (tid == 0) { hdr[2 * row] = (unsigned int)s_cnt; hdr[2 * row + 1] = bnd; }
}

// ---------------------------------------------------------------------------
// Kernel 2 (NEW): sequential inhibition scan over CANDIDATES only.
// Inhibition state (16384 fp32) lives in LDS; per step: ~cnt<=2048 candidate
// keys (2/thread, records prefetched one row ahead), 1 histogram pass +
// wave0 refine -> top-64 among candidates; exactness certificate:
// min selected key >= boundary<<14  (excluded units provably below).
// On failure (or candidate overflow): full-row fallback (validated path).
// ---------------------------------------------------------------------------
__global__ __launch_bounds__(1024) void scan_cand(const float* __restrict__ enc,
                                                  const unsigned long long* __restrict__ rec,
                                                  const unsigned int* __restrict__ hdr,
                                                  int* __restrict__ seli) {
  const int tid = threadIdx.x;
  __shared__ float inhib[H_UNITS];            // 64 KB
  __shared__ unsigned int histA[2048];        // 8 KB
  __shared__ unsigned int histB[2048];        // 8 KB
  __shared__ unsigned long long cand[CAND_MAX];  // 16 KB
  __shared__ unsigned int hist128[128];
  __shared__ int selJ[64];
  __shared__ unsigned long long selK[64];
  __shared__ int s_b1, s_nsel, s_ccnt, s_wtmp, s_fall;
  __shared__ int s_b2, s_ab2, s_b3, s_ab3, s_tiecnt;
  __shared__ unsigned int s_abU;

  // zero inhibition
#pragma unroll
  for (int q = 0; q < QPT; ++q) inhib[q * 1024 + tid] = 0.0f;
  __syncthreads();

  // preload row-0 candidate data
  unsigned long long pre0 = rec[tid];
  unsigned long long pre1 = rec[1024 + tid];
  unsigned int preCnt = hdr[0];
  unsigned int preBnd = hdr[1];

  for (int t = 0; t < B_ROWS; ++t) {
    const unsigned long long r0 = pre0, r1 = pre1;
    const int cnt = (int)preCnt;
    const unsigned int bnd = preBnd;
    int* srow = seli + t * 64;

    // prefetch next row's records/header (consumed next iteration)
    const int tn = (t + 1 < B_ROWS) ? (t + 1) : t;
    pre0 = rec[(size_t)tn * CAND_MAX + tid];
    pre1 = rec[(size_t)tn * CAND_MAX + 1024 + tid];
    preCnt = hdr[2 * tn];
    preBnd = hdr[2 * tn + 1];

    const bool rowfast = (cnt <= CAND_MAX);

    // zero hist + init scalars + compute candidate keys (reads inhib)
    histA[tid] = 0u; histA[1024 + tid] = 0u;
    histB[tid] = 0u; histB[1024 + tid] = 0u;
    if (tid == 0) { s_nsel = 0; s_ccnt = 0; s_fall = rowfast ? 0 : 1; }

    unsigned long long k0 = 0ull, k1 = 0ull;
    int j0 = 0, j1 = 0;
    bool v0 = false, v1 = false;
    if (rowfast) {
      v0 = (tid < cnt);
      v1 = (1024 + tid < cnt);
      if (v0) {
        j0 = (int)(r0 & 0xFFFFull);
        float e = __uint_as_float((unsigned int)(r0 >> 32));
        float rr = __fmul_rn(fabsf(e), __fsub_rn(1.0f, inhib[j0]));  // np-exact
        k0 = (((unsigned long long)orderable(rr)) << 14) | (unsigned long long)(16383 - j0);
      }
      if (v1) {
        j1 = (int)(r1 & 0xFFFFull);
        float e = __uint_as_float((unsigned int)(r1 >> 32));
        float rr = __fmul_rn(fabsf(e), __fsub_rn(1.0f, inhib[j1]));
        k1 = (((unsigned long long)orderable(rr)) << 14) | (unsigned long long)(16383 - j1);
      }
    }
    __syncthreads();  // B1

    if (rowfast) {
      unsigned int* hrep = ((tid >> 6) & 1) ? histB : histA;
      if (v0) { int b = (int)(k0 >> 35); atomicAdd(&hrep[SWZ(b)], 1u); }
      if (v1) { int b = (int)(k1 >> 35); atomicAdd(&hrep[SWZ(b)], 1u); }
    }
    __syncthreads();  // B2

    if (rowfast && tid < 64) wave_find2048(histA, histB, 64u, tid, &s_b1, &s_abU);
    __syncthreads();  // B3

    if (rowfast) {
      const unsigned int b1 = (unsigned int)s_b1;
      if (v0) {
        unsigned int bb = (unsigned int)(k0 >> 35);
        if (bb > b1) {
          int slot = atomicAdd(&s_nsel, 1);
          srow[slot] = j0; selJ[slot] = j0; selK[slot] = k0;
        } else if (bb == b1) {
          int p = atomicAdd(&s_ccnt, 1);
          if (p < CAND_MAX) cand[p] = k0;
        }
      }
      if (v1) {
        unsigned int bb = (unsigned int)(k1 >> 35);
        if (bb > b1) {
          int slot = atomicAdd(&s_nsel, 1);
          srow[slot] = j1; selJ[slot] = j1; selK[slot] = k1;
        } else if (bb == b1) {
          int p = atomicAdd(&s_ccnt, 1);
          if (p < CAND_MAX) cand[p] = k1;
        }
      }
    }
    __syncthreads();  // B4

    if (rowfast && tid < 64) {
      int needc = 64 - s_nsel;
      int Cc = s_ccnt;  // <= cnt <= CAND_MAX, cannot overflow
      wave_refine(cand, hist128, Cc, needc, srow, selJ, selK, &s_nsel, &s_wtmp);
      // exactness certificate: min selected key vs boundary bound
      unsigned long long kk = selK[tid];
#pragma unroll
      for (int d = 32; d >= 1; d >>= 1) {
        unsigned long long o = __shfl_down(kk, d);
        if (o < kk) kk = o;
      }
      if (tid == 0) s_fall = (kk < (((unsigned long long)bnd) << 14)) ? 1 : 0;
    }
    __syncthreads();  // B5

    if (s_fall) {
      // ------------------ FULL-ROW FALLBACK (validated path) ------------------
      if (tid == 0) { s_nsel = 0; s_ccnt = 0; }
      histA[tid] = 0u; histA[1024 + tid] = 0u;
      histB[tid] = 0u; histB[1024 + tid] = 0u;
      const float* erow = enc + (size_t)t * H_UNITS;
      unsigned int ok[QPT];
#pragma unroll
      for (int q = 0; q < QPT; ++q) {
        int j = q * 1024 + tid;
        float e = erow[j];
        float rr = __fmul_rn(fabsf(e), __fsub_rn(1.0f, inhib[j]));
        ok[q] = orderable(rr);
      }
      __syncthreads();
      unsigned int* hrep = ((tid >> 6) & 1) ? histB : histA;
#pragma unroll
      for (int q = 0; q < QPT; ++q) {
        int b = (int)(ok[q] >> 21);
        atomicAdd(&hrep[SWZ(b)], 1u);
      }
      __syncthreads();
      if (tid < 64) wave_find2048(histA, histB, 64u, tid, &s_b1, &s_abU);
      __syncthreads();
      const unsigned int b1 = (unsigned int)s_b1;
#pragma unroll
      for (int q = 0; q < QPT; ++q) {
        unsigned int o = ok[q];
        unsigned int bb = o >> 21;
        int j = q * 1024 + tid;
        if (bb > b1) {
          int slot = atomicAdd(&s_nsel, 1);
          srow[slot] = j; selJ[slot] = j;
        } else if (bb == b1) {
          int p = atomicAdd(&s_ccnt, 1);
          if (p < CAND_MAX) cand[p] = (((unsigned long long)o) << 14) | (unsigned long long)(16383 - j);
        }
      }
      __syncthreads();
      const int Cc0 = s_ccnt;
      if (Cc0 <= CAND_MAX) {
        if (tid < 64) {
          int needc = 64 - s_nsel;
          wave_refine(cand, hist128, Cc0, needc, srow, selJ, selK, &s_nsel, &s_wtmp);
        }
      } else {
        // slow 3-pass (proven): 11+11+10-bit radix within bucket b1
        int need2 = 64 - s_nsel;
        for (int i = tid; i < 2048; i += 1024) histA[i] = 0u;
        histB[tid] = 0u;
        if (tid == 0) s_tiecnt = 0;
        __syncthreads();
#pragma unroll
        for (int q = 0; q < QPT; ++q)
          if ((ok[q] >> 21) == b1) atomicAdd(&histA[(ok[q] >> 10) & 0x7FFu], 1u);
        __syncthreads();
        suffix_find(histA, 32, need2, tid, &s_b2, &s_ab2);
        __syncthreads();
        const unsigned int pfx = (b1 << 21) | ((unsigned int)s_b2 << 10);
        const int need3 = need2 - s_ab2;
#pragma unroll
        for (int q = 0; q < QPT; ++q)
          if ((ok[q] & 0xFFFFFC00u) == pfx) atomicAdd(&histB[ok[q] & 0x3FFu], 1u);
        __syncthreads();
        suffix_find(histB, 16, need3, tid, &s_b3, &s_ab3);
        __syncthreads();
        const unsigned int ostar = pfx | (unsigned int)s_b3;
        const int tneed = need3 - s_ab3;
        int* tl = (int*)cand;
#pragma unroll
        for (int q = 0; q < QPT; ++q) {
          unsigned int o = ok[q];
          int j = q * 1024 + tid;
          if (o > ostar && (o >> 21) == b1) {
            int slot = atomicAdd(&s_nsel, 1);
            srow[slot] = j; selJ[slot] = j;
          } else if (o == ostar) {
            int p = atomicAdd(&s_tiecnt, 1);
            if (p < 1024) tl[p] = j;
          }
        }
        __syncthreads();
        if (tid == 0) {
          int tc = s_tiecnt; if (tc > 1024) tc = 1024;
          for (int k = 0; k < tneed; ++k) {
            int bi = 0x7FFFFFFF, bpos = 0;
            for (int i = 0; i < tc; ++i) {
              int v = tl[i];
              if (v < bi) { bi = v; bpos = i; }
            }
            tl[bpos] = 0x7FFFFFFF;
            selJ[64 - tneed + k] = bi;
            srow[64 - tneed + k] = bi;
          }
        }
      }
      __syncthreads();  // end fallback
    }

    // inhibition update: decay all (np-exact), then +1 for selected
#pragma unroll
    for (int q = 0; q < QPT; ++q) {
      int j = q * 1024 + tid;
      inhib[j] = __fmul_rn(inhib[j], 0.95f);
    }
    __syncthreads();  // B7
    if (tid < 64) {
      int j = selJ[tid];
      inhib[j] = __fadd_rn(inhib[j], 1.0f);
    }
    __syncthreads();  // B8
  }
}

// ---------------------------------------------------------------------------
// Kernel 2-OLD (ws-gate fallback): validated round-1 scan, kept verbatim.
// ---------------------------------------------------------------------------
__global__ __launch_bounds__(1024) void scan_radix(const float* __restrict__ enc,
                                                   int* __restrict__ seli) {
  const int tid = threadIdx.x;
  __shared__ unsigned int histA[2048];
  __shared__ unsigned int histB[2048];
  __shared__ unsigned int hist128[128];
  __shared__ unsigned int bmap[2][512];
  __shared__ unsigned long long cand[4096];
  __shared__ int s_b1, s_nsel, s_ccnt, s_wtmp;
  __shared__ int s_b2, s_ab2, s_b3, s_ab3, s_tiecnt;
  __shared__ unsigned int s_abU;

  float iv[QPT];
  float ec[QPT];
#pragma unroll
  for (int q = 0; q < QPT; ++q) iv[q] = 0.0f;
#pragma unroll
  for (int q = 0; q < QPT; ++q) ec[q] = enc[q * 1024 + tid];

  for (int t = 0; t < B_ROWS; ++t) {
    const int cur = t & 1;
    unsigned int* bm = bmap[cur];
    int* srow = seli + t * 64;

    for (int i = tid; i < 2048; i += 1024) { histA[i] = 0u; histB[i] = 0u; }
    if (tid < 512) bm[tid] = 0u;
    if (tid == 0) { s_nsel = 0; s_ccnt = 0; }
    unsigned int ok[QPT];
#pragma unroll
    for (int q = 0; q < QPT; ++q) {
      float r = __fmul_rn(fabsf(ec[q]), __fsub_rn(1.0f, iv[q]));
      ok[q] = orderable(r);
    }
    __syncthreads();

    const int tn = (t + 1 < B_ROWS) ? (t + 1) : t;
    const float* nrow = enc + (size_t)tn * H_UNITS;
    float en[QPT];
#pragma unroll
    for (int q = 0; q < QPT; ++q) en[q] = nrow[q * 1024 + tid];

    unsigned int* hrep = ((tid >> 6) & 1) ? histB : histA;
#pragma unroll
    for (int q = 0; q < QPT; ++q) {
      int b = (int)(ok[q] >> 21);
      atomicAdd(&hrep[SWZ(b)], 1u);
    }
    __syncthreads();

    if (tid < 64) wave_find2048(histA, histB, 64u, tid, &s_b1, &s_abU);
    __syncthreads();

    const unsigned int b1 = (unsigned int)s_b1;
#pragma unroll
    for (int q = 0; q < QPT; ++q) {
      unsigned int o = ok[q];
      unsigned int bb = o >> 21;
      if (bb >= b1) {
        int j = q * 1024 + tid;
        if (bb > b1) {
          int slot = atomicAdd(&s_nsel, 1);
          srow[slot] = j;
          atomicOr(&bm[j >> 5], 1u << (j & 31));
        } else {
          int p = atomicAdd(&s_ccnt, 1);
          if (p < 4096)
            cand[p] = (((unsigned long long)o) << 14) | (unsigned long long)(16383 - j);
        }
      }
    }
    __syncthreads();

    const int Cc0 = s_ccnt;
    if (Cc0 <= 4096) {
      if (tid < 64) {
        int needc = 64 - s_nsel;
        int Cc = Cc0;
        int shift = 28;
        while (true) {
          if (Cc <= needc) {
            for (int s = tid; s < Cc; s += 64) {
              unsigned long long k = cand[s];
              int j = 16383 - (int)(k & 0x3FFFull);
              int slot = atomicAdd(&s_nsel, 1);
              srow[slot] = j;
              atomicOr(&bm[j >> 5], 1u << (j & 31));
            }
            break;
          }
          hist128[tid] = 0u;
          hist128[tid + 64] = 0u;
          if (tid == 0) s_wtmp = 0;
          asm volatile("s_waitcnt lgkmcnt(0)" ::: "memory");
          for (int s = tid; s < Cc; s += 64) {
            int ch = (int)((cand[s] >> shift) & 127ull);
            atomicAdd(&hist128[ch], 1u);
          }
          asm volatile("s_waitcnt lgkmcnt(0)" ::: "memory");
          unsigned int c0 = hist128[2 * tid];
          unsigned int c1 = hist128[2 * tid + 1];
          unsigned int ps = c0 + c1;
#pragma unroll
          for (int d = 1; d < 64; d <<= 1) {
            unsigned int o = __shfl_down(ps, d);
            if (tid + d < 64) ps += o;
          }
          unsigned int incl = ps;
          unsigned int incln = __shfl_down(incl, 1);
          if (tid == 63) incln = 0u;
          unsigned int smid = incl - c0;
          bool crossHi = (smid >= (unsigned int)needc) && (incln < (unsigned int)needc);
          bool crossLo = (incl >= (unsigned int)needc) && (smid < (unsigned int)needc);
          unsigned long long bal = __ballot(crossHi || crossLo);
          int gl = __ffsll(bal) - 1;
          int hiF = __shfl((int)crossHi, gl);
          int vstar = 2 * gl + hiF;
          unsigned int aboveCh = (unsigned int)__shfl((int)(hiF ? incln : smid), gl);
          for (int s = tid; s < Cc; s += 64) {
            unsigned long long k = cand[s];
            int ch = (int)((k >> shift) & 127ull);
            if (ch > vstar) {
              int j = 16383 - (int)(k & 0x3FFFull);
              int slot = atomicAdd(&s_nsel, 1);
              srow[slot] = j;
              atomicOr(&bm[j >> 5], 1u << (j & 31));
            } else if (ch == vstar) {
              int p = atomicAdd(&s_wtmp, 1);
              cand[p] = k;
            }
          }
          asm volatile("s_waitcnt lgkmcnt(0)" ::: "memory");
          needc -= (int)aboveCh;
          Cc = s_wtmp;
          shift -= 7;
        }
      }
    } else {
      int need2 = 64 - s_nsel;
      for (int i = tid; i < 2048; i += 1024) histA[i] = 0u;
      histB[tid] = 0u;
      if (tid == 0) s_tiecnt = 0;
      __syncthreads();
#pragma unroll
      for (int q = 0; q < QPT; ++q)
        if ((ok[q] >> 21) == b1) atomicAdd(&histA[(ok[q] >> 10) & 0x7FFu], 1u);
      __syncthreads();
      suffix_find(histA, 32, need2, tid, &s_b2, &s_ab2);
      __syncthreads();
      const unsigned int pfx = (b1 << 21) | ((unsigned int)s_b2 << 10);
      const int need3 = need2 - s_ab2;
#pragma unroll
      for (int q = 0; q < QPT; ++q)
        if ((ok[q] & 0xFFFFFC00u) == pfx) atomicAdd(&histB[ok[q] & 0x3FFu], 1u);
      __syncthreads();
      suffix_find(histB, 16, need3, tid, &s_b3, &s_ab3);
      __syncthreads();
      const unsigned int ostar = pfx | (unsigned int)s_b3;
      const int tneed = need3 - s_ab3;
      int* tl = (int*)cand;
#pragma unroll
      for (int q = 0; q < QPT; ++q) {
        unsigned int o = ok[q];
        int j = q * 1024 + tid;
        if (o > ostar && (o >> 21) == b1) {
          int slot = atomicAdd(&s_nsel, 1);
          srow[slot] = j;
          atomicOr(&bm[j >> 5], 1u << (j & 31));
        } else if (o == ostar) {
          int p = atomicAdd(&s_tiecnt, 1);
          if (p < 1024) tl[p] = j;
        }
      }
      __syncthreads();
      if (tid == 0) {
        int tc = s_tiecnt; if (tc > 1024) tc = 1024;
        for (int k = 0; k < tneed; ++k) {
          int bi = 0x7FFFFFFF, bpos = 0;
          for (int i = 0; i < tc; ++i) {
            int v = tl[i];
            if (v < bi) { bi = v; bpos = i; }
          }
          tl[bpos] = 0x7FFFFFFF;
          bmap[cur][bi >> 5] |= (1u << (bi & 31));
          srow[64 - tneed + k] = bi;
        }
      }
    }
    __syncthreads();

#pragma unroll
    for (int q = 0; q < QPT; ++q) {
      int j = q * 1024 + tid;
      float m = ((bm[j >> 5] >> (j & 31)) & 1u) ? 1.0f : 0.0f;
      iv[q] = __fadd_rn(__fmul_rn(iv[q], 0.95f), m);
      ec[q] = en[q];
    }
    __syncthreads();
  }
}

// ---------------------------------------------------------------------------
// Kernel 3: final top-64 over filtered = enc * mask, brute-force exact.
// (unchanged -- validated)
// ---------------------------------------------------------------------------
__global__ __launch_bounds__(1024) void final_brute(const int* __restrict__ seli,
                                                    float* __restrict__ out) {
  const int row = blockIdx.x;
  const int tid = threadIdx.x;
  __shared__ unsigned long long wmax[16];
  __shared__ unsigned long long s_win;
  __shared__ int wlist[64];
  __shared__ unsigned int bmap[512];
  const float* erow = out + (size_t)row * H_UNITS;

  if (tid < 512) bmap[tid] = 0u;
  __syncthreads();
  if (tid < 64) {
    int idx = seli[row * 64 + tid];
    atomicOr(&bmap[idx >> 5], 1u << (idx & 31));
  }
  __syncthreads();

  unsigned long long key[16];
  unsigned long long lmax = 0ull;
#pragma unroll
  for (int q = 0; q < 16; ++q) {
    int j = q * 1024 + tid;
    float e = erow[j];
    bool sel = (bmap[j >> 5] >> (j & 31)) & 1u;
    unsigned int eb = __float_as_uint(e);
    float f = __uint_as_float(sel ? eb : (eb & 0x80000000u));  // ±0 keeps sign
    unsigned long long k = make_key(f, j);
    key[q] = k;
    if (k > lmax) lmax = k;
  }
  __syncthreads();

  float4 z = make_float4(0.0f, 0.0f, 0.0f, 0.0f);
  float4* o4 = reinterpret_cast<float4*>(out + (size_t)row * H_UNITS);
  for (int i = tid; i < H_UNITS / 4; i += 1024) o4[i] = z;
  __syncthreads();

  for (int round = 0; round < 64; ++round) {
    unsigned long long v = lmax;
#pragma unroll
    for (int d = 32; d >= 1; d >>= 1) {
      unsigned long long o = __shfl_down(v, d);
      if (o > v) v = o;
    }
    if ((tid & 63) == 0) wmax[tid >> 6] = v;
    __syncthreads();
    if (tid == 0) {
      unsigned long long m = wmax[0];
#pragma unroll
      for (int w = 1; w < 16; ++w)
        if (wmax[w] > m) m = wmax[w];
      s_win = m;
      wlist[round] = 16383 - (int)(m & 0x3FFFull);
    }
    __syncthreads();
    unsigned long long Wk = s_win;
    if (lmax == Wk) {
      unsigned long long nm = 0ull;
#pragma unroll
      for (int q = 0; q < 16; ++q) {
        unsigned long long k = key[q];
        if (k < Wk && k > nm) nm = k;
      }
      lmax = nm;
    }
  }
  __syncthreads();
  if (tid < 64) out[(size_t)row * H_UNITS + wlist[tid]] = 1.0f;
}

// ---------------------------------------------------------------------------
extern "C" void kernel_launch(void* const* d_in, const int* in_sizes, int n_in,
                              void* d_out, int out_size, void* d_ws, size_t ws_size,
                              hipStream_t stream) {
  const float* inputs = (const float*)d_in[0];   // [512][2048] fp32
  const float* W = (const float*)d_in[1];        // [16384][2048] fp32
  float* out = (float*)d_out;                    // [512][16384] fp32 -- also enc scratch
  char* ws = (char*)d_ws;

  // ws layout: [0] seli 128KB | [131072] hdr 4KB | [135168] rec 8MB
  int* seli = (int*)(ws);
  unsigned int* hdr = (unsigned int*)(ws + 131072);
  unsigned long long* rec = (unsigned long long*)(ws + 135168);
  const size_t WS_NEEDED = 135168 + (size_t)B_ROWS * CAND_MAX * 8;  // 8,523,776

  float* enc = out;  // encoding scratch lives in d_out

  gemm_kernel<<<dim3(H_UNITS / 64, B_ROWS / 64), 256, 0, stream>>>(inputs, W, enc);
  if (ws_size >= WS_NEEDED) {
    precomp_cand<<<B_ROWS, 1024, 0, stream>>>(enc, rec, hdr);
    scan_cand<<<1, 1024, 0, stream>>>(enc, rec, hdr, seli);
  } else {
    scan_radix<<<1, 1024, 0, stream>>>(enc, seli);
  }
  final_brute<<<B_ROWS, 1024, 0, stream>>>(seli, out);
}

// Round 3
// 2412.962 us; speedup vs baseline: 5.1675x; 1.7021x over previous
//
#include <hip/hip_runtime.h>
#include <math.h>
#include <stdint.h>

// Problem constants
#define B_ROWS 512
#define H_UNITS 16384
#define K_IN 2048
#define K_SEL 64
#define QPT 16  // keys per thread = 16384 / 1024
#define CAND_MAX 2048
#define SWZ(b) ((b) ^ (((b) >> 5) & 31))

// ---------------------------------------------------------------------------
// Kernel 1: encoding = inputs @ W^T  (fp32 mul, 64-chunk fp32 acc, fp64 chunk sum)
// (unchanged from the PASSING version -- exactness-validated, do not touch)
// ---------------------------------------------------------------------------
__global__ __launch_bounds__(256) void gemm_kernel(const float* __restrict__ A,
                                                   const float* __restrict__ W,
                                                   float* __restrict__ C) {
  __shared__ __align__(16) float As[64][68];
  __shared__ __align__(16) float Bs[64][68];
  const int tid = threadIdx.x;
  const int tx = tid & 15, ty = tid >> 4;
  const int bm = blockIdx.y * 64, bn = blockIdx.x * 64;

  double accd[16];
#pragma unroll
  for (int i = 0; i < 16; ++i) accd[i] = 0.0;

  const float* Ab = A + (size_t)bm * K_IN;
  const float* Wb = W + (size_t)bn * K_IN;

  for (int k0 = 0; k0 < K_IN; k0 += 64) {
#pragma unroll
    for (int p = 0; p < 4; ++p) {
      int id = p * 256 + tid;
      int m = id >> 4;
      int kq = (id & 15) << 2;
      float4 a = *reinterpret_cast<const float4*>(Ab + (size_t)m * K_IN + k0 + kq);
      As[kq + 0][m] = a.x; As[kq + 1][m] = a.y; As[kq + 2][m] = a.z; As[kq + 3][m] = a.w;
      float4 b = *reinterpret_cast<const float4*>(Wb + (size_t)m * K_IN + k0 + kq);
      Bs[kq + 0][m] = b.x; Bs[kq + 1][m] = b.y; Bs[kq + 2][m] = b.z; Bs[kq + 3][m] = b.w;
    }
    __syncthreads();

    float accf[16];
#pragma unroll
    for (int i = 0; i < 16; ++i) accf[i] = 0.0f;

#pragma unroll 16
    for (int kk = 0; kk < 64; ++kk) {
      float4 av = *reinterpret_cast<const float4*>(&As[kk][ty << 2]);
      float4 bv = *reinterpret_cast<const float4*>(&Bs[kk][tx << 2]);
      accf[0]  += av.x * bv.x; accf[1]  += av.x * bv.y; accf[2]  += av.x * bv.z; accf[3]  += av.x * bv.w;
      accf[4]  += av.y * bv.x; accf[5]  += av.y * bv.y; accf[6]  += av.y * bv.z; accf[7]  += av.y * bv.w;
      accf[8]  += av.z * bv.x; accf[9]  += av.z * bv.y; accf[10] += av.z * bv.z; accf[11] += av.z * bv.w;
      accf[12] += av.w * bv.x; accf[13] += av.w * bv.y; accf[14] += av.w * bv.z; accf[15] += av.w * bv.w;
    }
#pragma unroll
    for (int i = 0; i < 16; ++i) accd[i] += (double)accf[i];
    __syncthreads();
  }

#pragma unroll
  for (int i = 0; i < 4; ++i) {
    size_t rowoff = (size_t)(bm + (ty << 2) + i) * H_UNITS + bn + (tx << 2);
    float4 o;
    o.x = (float)accd[i * 4 + 0]; o.y = (float)accd[i * 4 + 1];
    o.z = (float)accd[i * 4 + 2]; o.w = (float)accd[i * 4 + 3];
    *reinterpret_cast<float4*>(C + rowoff) = o;
  }
}

// ---------------------------------------------------------------------------
// XLA float total order as u32: monotone bitcast (sign-magnitude flip).
// ---------------------------------------------------------------------------
__device__ __forceinline__ unsigned int orderable(float x) {
  unsigned int u = __float_as_uint(x);
  return u ^ ((u & 0x80000000u) ? 0xFFFFFFFFu : 0x80000000u);
}

__device__ __forceinline__ unsigned long long make_key(float r, int j) {
  unsigned int u = orderable(r);
  return (((unsigned long long)u) << 14) | (unsigned long long)(16383 - j);
}

// ---------------------------------------------------------------------------
// Serial suffix bucket find (validated) -- used by slow3 path.
// ---------------------------------------------------------------------------
__device__ __forceinline__ void suffix_find(const unsigned int* hist, int CH, int need,
                                            int tid, int* s_b, int* s_above) {
  if (tid < 64) {
    unsigned int s = 0;
    for (int q = 0; q < CH; ++q) s += hist[tid * CH + q];
#pragma unroll
    for (int d = 1; d < 64; d <<= 1) {
      unsigned int o = __shfl_down(s, d);
      if (tid + d < 64) s += o;
    }
    unsigned int snext = __shfl_down(s, 1);
    if (tid == 63) snext = 0;
    bool cross = (s >= (unsigned int)need) && (snext < (unsigned int)need);
    unsigned long long bal = __ballot(cross);
    int g = __ffsll(bal) - 1;
    if (tid == g) {
      unsigned int acc = snext;
      int b = g * CH;
      for (int q = CH - 1; q >= 0; --q) {
        unsigned int c = hist[g * CH + q];
        if (acc + c >= (unsigned int)need) { b = g * CH + q; break; }
        acc += c;
      }
      *s_b = b; *s_above = (int)acc;
    }
  }
}

// ---------------------------------------------------------------------------
// In-wave (tid<64) suffix find over 2048 swizzled buckets, TWO replicas.
// (validated -- fallback + precomp use)
// ---------------------------------------------------------------------------
__device__ __forceinline__ void wave_find2048(const unsigned int* ha, const unsigned int* hb,
                                              unsigned int need, int tid,
                                              int* s_b, unsigned int* s_above) {
  unsigned int s = 0;
  const int base = tid << 5;
#pragma unroll
  for (int q = 0; q < 32; ++q) {
    int b = base + q;
    int a = SWZ(b);
    s += ha[a] + hb[a];
  }
  unsigned int si = s;
#pragma unroll
  for (int d = 1; d < 64; d <<= 1) {
    unsigned int o = __shfl_down(si, d);
    if (tid + d < 64) si += o;
  }
  unsigned int snext = __shfl_down(si, 1);
  if (tid == 63) snext = 0u;
  bool cross = (si >= need) && (snext < need);
  unsigned long long bal = __ballot(cross);
  int g = __ffsll(bal) - 1;
  unsigned int sng = __shfl(snext, g);
  unsigned int c;
  {
    int b = (g << 5) + (tid & 31);
    int a = SWZ(b);
    c = ha[a] + hb[a];
  }
  unsigned int ti2 = c;
#pragma unroll
  for (int d = 1; d < 32; d <<= 1) {
    unsigned int o = __shfl_down(ti2, d);
    if ((tid & 31) + d < 32) ti2 += o;
  }
  unsigned int incl = sng + ti2;
  unsigned int incln = __shfl_down(incl, 1);
  if ((tid & 31) == 31) incln = sng;
  bool cr2 = (tid < 32) && (incl >= need) && (incln < need);
  unsigned long long bal2 = __ballot(cr2);
  int q2 = __ffsll(bal2) - 1;
  if (tid == q2) { *s_b = (g << 5) + q2; *s_above = incln; }
}

// ---------------------------------------------------------------------------
// Same find, SINGLE replica (fast-path histogram is spread -> one replica).
// ---------------------------------------------------------------------------
__device__ __forceinline__ void wave_find_single(const unsigned int* h, unsigned int need,
                                                 int tid, int* s_b, unsigned int* s_above) {
  unsigned int s = 0;
  const int base = tid << 5;
#pragma unroll
  for (int q = 0; q < 32; ++q) s += h[SWZ(base + q)];
  unsigned int si = s;
#pragma unroll
  for (int d = 1; d < 64; d <<= 1) {
    unsigned int o = __shfl_down(si, d);
    if (tid + d < 64) si += o;
  }
  unsigned int snext = __shfl_down(si, 1);
  if (tid == 63) snext = 0u;
  bool cross = (si >= need) && (snext < need);
  unsigned long long bal = __ballot(cross);
  int g = __ffsll(bal) - 1;
  unsigned int sng = __shfl(snext, g);
  unsigned int c = h[SWZ((g << 5) + (tid & 31))];
  unsigned int ti2 = c;
#pragma unroll
  for (int d = 1; d < 32; d <<= 1) {
    unsigned int o = __shfl_down(ti2, d);
    if ((tid & 31) + d < 32) ti2 += o;
  }
  unsigned int incl = sng + ti2;
  unsigned int incln = __shfl_down(incl, 1);
  if ((tid & 31) == 31) incln = sng;
  bool cr2 = (tid < 32) && (incl >= need) && (incln < need);
  unsigned long long bal2 = __ballot(cr2);
  int q2 = __ffsll(bal2) - 1;
  if (tid == q2) { *s_b = (g << 5) + q2; *s_above = incln; }
}

// ---------------------------------------------------------------------------
// Wave0 refine over full 46-bit keys sharing top-11 bits, PING-PONG buffers
// (read half rb, write half rb^2048 -- removes in-place compaction race).
// Fallback path use. Emits j into srow+selJ.
// ---------------------------------------------------------------------------
__device__ __forceinline__ void wave_refine_pp(unsigned long long* cand, unsigned int* hist128,
                                               int Cc, int needc, int* srow, int* selJ,
                                               int* s_nsel, int* s_wtmp) {
  const int tid = threadIdx.x;  // < 64
  int shift = 28;
  int rb = 0;
  while (true) {
    if (Cc <= needc) {
      for (int s = tid; s < Cc; s += 64) {
        unsigned long long k = cand[rb + s];
        int j = 16383 - (int)(k & 0x3FFFull);
        int slot = atomicAdd(s_nsel, 1);
        srow[slot] = j; selJ[slot] = j;
      }
      break;
    }
    hist128[tid] = 0u;
    hist128[tid + 64] = 0u;
    if (tid == 0) *s_wtmp = 0;
    asm volatile("s_waitcnt lgkmcnt(0)" ::: "memory");
    for (int s = tid; s < Cc; s += 64) {
      int ch = (int)((cand[rb + s] >> shift) & 127ull);
      atomicAdd(&hist128[ch], 1u);
    }
    asm volatile("s_waitcnt lgkmcnt(0)" ::: "memory");
    unsigned int c0 = hist128[2 * tid];
    unsigned int c1 = hist128[2 * tid + 1];
    unsigned int ps = c0 + c1;
#pragma unroll
    for (int d = 1; d < 64; d <<= 1) {
      unsigned int o = __shfl_down(ps, d);
      if (tid + d < 64) ps += o;
    }
    unsigned int incl = ps;
    unsigned int incln = __shfl_down(incl, 1);
    if (tid == 63) incln = 0u;
    unsigned int smid = incl - c0;
    bool crossHi = (smid >= (unsigned int)needc) && (incln < (unsigned int)needc);
    bool crossLo = (incl >= (unsigned int)needc) && (smid < (unsigned int)needc);
    unsigned long long bal = __ballot(crossHi || crossLo);
    int gl = __ffsll(bal) - 1;
    int hiF = __shfl((int)crossHi, gl);
    int vstar = 2 * gl + hiF;
    unsigned int aboveCh = (unsigned int)__shfl((int)(hiF ? incln : smid), gl);
    int wb = rb ^ 2048;
    for (int s = tid; s < Cc; s += 64) {
      unsigned long long k = cand[rb + s];
      int ch = (int)((k >> shift) & 127ull);
      if (ch > vstar) {
        int j = 16383 - (int)(k & 0x3FFFull);
        int slot = atomicAdd(s_nsel, 1);
        srow[slot] = j; selJ[slot] = j;
      } else if (ch == vstar) {
        int p = atomicAdd(s_wtmp, 1);
        cand[wb + p] = k;
      }
    }
    asm volatile("s_waitcnt lgkmcnt(0)" ::: "memory");
    needc -= (int)aboveCh;
    Cc = *s_wtmp;
    rb = wb;
    shift = (shift >= 7) ? shift - 7 : 0;
  }
}

// ---------------------------------------------------------------------------
// Kernel 1.5: per-row candidate precompute, full-GPU parallel.
// Boundary bnd with count in [1024, ~2048]; records (e_bits<<32|j); plus
// row o_max -> per-row bucket shift so (o_max-bnd)>>shift < 2048
// (mantissa-aligned fast-path bucketing).
// hdr[4r] = cnt, hdr[4r+1] = bnd, hdr[4r+2] = shift.
// ---------------------------------------------------------------------------
__global__ __launch_bounds__(1024) void precomp_cand(const float* __restrict__ enc,
                                                     unsigned long long* __restrict__ rec,
                                                     unsigned int* __restrict__ hdr) {
  const int row = blockIdx.x;
  const int tid = threadIdx.x;
  __shared__ unsigned int hA[2048], hB[2048], h2a[2048], h2b[2048];
  __shared__ int s_b1; __shared__ unsigned int s_ab1;
  __shared__ int s_b2; __shared__ unsigned int s_ab2;
  __shared__ int s_cnt;
  __shared__ unsigned int s_omax;
  const float* erow = enc + (size_t)row * H_UNITS;

  unsigned int ob[QPT], eb[QPT];
  for (int i = tid; i < 2048; i += 1024) { hA[i] = 0u; hB[i] = 0u; h2a[i] = 0u; h2b[i] = 0u; }
  if (tid == 0) { s_cnt = 0; s_omax = 0u; }
  unsigned int lmax = 0u;
#pragma unroll
  for (int q = 0; q < QPT; ++q) {
    int j = q * 1024 + tid;
    float e = erow[j];
    eb[q] = __float_as_uint(e);
    ob[q] = orderable(fabsf(e));
    if (ob[q] > lmax) lmax = ob[q];
  }
  __syncthreads();

  atomicMax(&s_omax, lmax);
  unsigned int* hrep = ((tid >> 6) & 1) ? hB : hA;
#pragma unroll
  for (int q = 0; q < QPT; ++q) {
    int b = (int)(ob[q] >> 21);
    atomicAdd(&hrep[SWZ(b)], 1u);
  }
  __syncthreads();
  if (tid < 64) wave_find2048(hA, hB, 1024u, tid, &s_b1, &s_ab1);
  __syncthreads();

  const unsigned int b1 = (unsigned int)s_b1;
  const unsigned int need2 = 1024u - s_ab1;
  unsigned int* h2rep = ((tid >> 6) & 1) ? h2b : h2a;
#pragma unroll
  for (int q = 0; q < QPT; ++q) {
    if ((ob[q] >> 21) == b1) {
      int b = (int)((ob[q] >> 10) & 0x7FFu);
      atomicAdd(&h2rep[SWZ(b)], 1u);
    }
  }
  __syncthreads();
  if (tid < 64) wave_find2048(h2a, h2b, need2, tid, &s_b2, &s_ab2);
  __syncthreads();

  const unsigned int bnd = (b1 << 21) | ((unsigned int)s_b2 << 10);
#pragma unroll
  for (int q = 0; q < QPT; ++q) {
    if (ob[q] >= bnd) {
      int p = atomicAdd(&s_cnt, 1);
      if (p < CAND_MAX)
        rec[(size_t)row * CAND_MAX + p] =
            (((unsigned long long)eb[q]) << 32) | (unsigned long long)(q * 1024 + tid);
    }
  }
  __syncthreads();
  if (tid == 0) {
    unsigned int span = s_omax - bnd;
    int bitpos = (span == 0u) ? -1 : (31 - __clz((int)span));
    unsigned int shift = (bitpos > 10) ? (unsigned int)(bitpos - 10) : 0u;
    hdr[4 * row + 0] = (unsigned int)s_cnt;
    hdr[4 * row + 1] = bnd;
    hdr[4 * row + 2] = shift;
  }
}

// ---------------------------------------------------------------------------
// Kernel 2: sequential inhibition scan over CANDIDATES, mantissa-aligned
// buckets. Per step (fast path, 5 barriers):
//   A: keys from inhib gather; spread 2048-bucket histogram (linear atomics,
//      SWZ layout).                                   B1
//   wave0: suffix find -> b1 (b1==0 -> fallback).     B2
//   C: all: bucket>b1 emit; ==b1 append u-key.        B3
//   D: wave0: refine passes (rarely needed) + wave tournament for needc
//      largest; waves1-15 CONCURRENTLY: inhib *= 0.95 + re-zero hist.  B4
//   E: +1 for selected; reset scalars.                B5
// Exactness: selections have o > bnd (b1>=1) and excluded units' keys are
// < bnd<<14 forever (r = fl(|e|*fl(1-i)) <= |e|, monotone rounding).
// Fallback: validated full-row path.
// ---------------------------------------------------------------------------
__global__ __launch_bounds__(1024) void scan_cand(const float* __restrict__ enc,
                                                  const unsigned long long* __restrict__ rec,
                                                  const unsigned int* __restrict__ hdr,
                                                  int* __restrict__ seli) {
  const int tid = threadIdx.x;
  __shared__ float inhib[H_UNITS];              // 64 KB
  __shared__ unsigned int fine[2048];           // 8 KB  (fast hist / fallback replica A)
  __shared__ unsigned int histB[2048];          // 8 KB  (fallback replica B / slow3)
  __shared__ unsigned long long cand[4096];     // 32 KB (ping-pong halves of 2048)
  __shared__ unsigned int hist128[128];
  __shared__ int selJ[64];
  __shared__ int s_b1, s_nsel, s_ccnt, s_wtmp;
  __shared__ unsigned int s_above;
  __shared__ int s_b2, s_ab2, s_b3, s_ab3, s_tiecnt;

  // init
#pragma unroll
  for (int q = 0; q < QPT; ++q) inhib[q * 1024 + tid] = 0.0f;
  fine[tid] = 0u; fine[1024 + tid] = 0u;
  histB[tid] = 0u; histB[1024 + tid] = 0u;
  if (tid == 0) { s_nsel = 0; s_ccnt = 0; }
  __syncthreads();

  unsigned long long pre0 = rec[tid];
  unsigned long long pre1 = rec[1024 + tid];
  unsigned int preCnt = hdr[0];
  unsigned int preBnd = hdr[1];
  unsigned int preShf = hdr[2];

  for (int t = 0; t < B_ROWS; ++t) {
    const unsigned long long r0 = pre0, r1 = pre1;
    const int cnt = (int)preCnt;
    const unsigned int bnd = preBnd;
    const int shift = (int)preShf;
    int* srow = seli + t * 64;

    const int tn = (t + 1 < B_ROWS) ? (t + 1) : t;
    pre0 = rec[(size_t)tn * CAND_MAX + tid];
    pre1 = rec[(size_t)tn * CAND_MAX + 1024 + tid];
    preCnt = hdr[4 * tn + 0];
    preBnd = hdr[4 * tn + 1];
    preShf = hdr[4 * tn + 2];

    const bool rowfast = (cnt <= CAND_MAX);

    // ---- phase A: keys + spread histogram ----
    bool v0 = false, v1 = false;
    unsigned int bb0 = 0, bb1v = 0;
    unsigned long long u0 = 0ull, u1 = 0ull;
    int j0 = 0, j1 = 0;
    if (rowfast) {
      v0 = (tid < cnt);
      v1 = (1024 + tid < cnt);
      if (v0) {
        j0 = (int)(r0 & 0xFFFFull);
        float e = __uint_as_float((unsigned int)(r0 >> 32));
        float rr = __fmul_rn(fabsf(e), __fsub_rn(1.0f, inhib[j0]));  // np-exact
        unsigned int o = orderable(rr);
        bb0 = (o >= bnd) ? ((o - bnd) >> shift) : 0u;
        u0 = (((unsigned long long)(o - bnd)) << 14) | (unsigned long long)(16383 - j0);
        atomicAdd(&fine[SWZ((int)bb0)], 1u);
      }
      if (v1) {
        j1 = (int)(r1 & 0xFFFFull);
        float e = __uint_as_float((unsigned int)(r1 >> 32));
        float rr = __fmul_rn(fabsf(e), __fsub_rn(1.0f, inhib[j1]));
        unsigned int o = orderable(rr);
        bb1v = (o >= bnd) ? ((o - bnd) >> shift) : 0u;
        u1 = (((unsigned long long)(o - bnd)) << 14) | (unsigned long long)(16383 - j1);
        atomicAdd(&fine[SWZ((int)bb1v)], 1u);
      }
    }
    __syncthreads();  // B1

    if (rowfast && tid < 64) wave_find_single(fine, 64u, tid, &s_b1, &s_above);
    __syncthreads();  // B2

    int b1 = 0;
    bool fastok = false;
    if (rowfast) { b1 = s_b1; fastok = (b1 > 0); }

    if (fastok) {
      // ---- phase C: collect ----
      if (v0) {
        if (bb0 > (unsigned int)b1) {
          int slot = atomicAdd(&s_nsel, 1);
          srow[slot] = j0; selJ[slot] = j0;
        } else if (bb0 == (unsigned int)b1) {
          int p = atomicAdd(&s_ccnt, 1);
          cand[p] = u0;
        }
      }
      if (v1) {
        if (bb1v > (unsigned int)b1) {
          int slot = atomicAdd(&s_nsel, 1);
          srow[slot] = j1; selJ[slot] = j1;
        } else if (bb1v == (unsigned int)b1) {
          int p = atomicAdd(&s_ccnt, 1);
          cand[p] = u1;
        }
      }
      __syncthreads();  // B3

      // ---- phase D: wave0 selection-finish || waves1-15 decay + re-zero ----
      if (tid < 64) {
        int needc = 64 - s_nsel;
        int Cc = s_ccnt;
        int rb = 0;
        int sr = shift + 7;
        while (Cc > 64 && Cc > needc) {
          hist128[tid] = 0u;
          hist128[tid + 64] = 0u;
          if (tid == 0) s_wtmp = 0;
          asm volatile("s_waitcnt lgkmcnt(0)" ::: "memory");
          for (int si = tid; si < Cc; si += 64) {
            int ch = (int)((cand[rb + si] >> sr) & 127ull);
            atomicAdd(&hist128[ch], 1u);
          }
          asm volatile("s_waitcnt lgkmcnt(0)" ::: "memory");
          unsigned int c0 = hist128[2 * tid];
          unsigned int c1 = hist128[2 * tid + 1];
          unsigned int ps = c0 + c1;
#pragma unroll
          for (int d = 1; d < 64; d <<= 1) {
            unsigned int o = __shfl_down(ps, d);
            if (tid + d < 64) ps += o;
          }
          unsigned int incl = ps;
          unsigned int incln = __shfl_down(incl, 1);
          if (tid == 63) incln = 0u;
          unsigned int smid = incl - c0;
          bool crossHi = (smid >= (unsigned int)needc) && (incln < (unsigned int)needc);
          bool crossLo = (incl >= (unsigned int)needc) && (smid < (unsigned int)needc);
          unsigned long long bal = __ballot(crossHi || crossLo);
          int gl = __ffsll(bal) - 1;
          int hiF = __shfl((int)crossHi, gl);
          int vstar = 2 * gl + hiF;
          unsigned int aboveCh = (unsigned int)__shfl((int)(hiF ? incln : smid), gl);
          int wb = rb ^ 2048;
          for (int si = tid; si < Cc; si += 64) {
            unsigned long long u = cand[rb + si];
            int ch = (int)((u >> sr) & 127ull);
            if (ch > vstar) {
              int jj = 16383 - (int)(u & 0x3FFFull);
              int slot = atomicAdd(&s_nsel, 1);
              srow[slot] = jj; selJ[slot] = jj;
            } else if (ch == vstar) {
              int p = atomicAdd(&s_wtmp, 1);
              cand[wb + p] = u;
            }
          }
          asm volatile("s_waitcnt lgkmcnt(0)" ::: "memory");
          needc -= (int)aboveCh;
          Cc = s_wtmp;
          rb = wb;
          sr = (sr >= 7) ? sr - 7 : 0;
        }
        if (Cc <= needc) {
          for (int si = tid; si < Cc; si += 64) {
            unsigned long long u = cand[rb + si];
            int jj = 16383 - (int)(u & 0x3FFFull);
            int slot = atomicAdd(&s_nsel, 1);
            srow[slot] = jj; selJ[slot] = jj;
          }
        } else {
          // wave tournament: needc largest among Cc (<=64) keys
          bool alive = (tid < Cc);
          unsigned long long myk = alive ? cand[rb + tid] : 0ull;
          for (int r = 0; r < needc; ++r) {
            unsigned long long v = myk;
#pragma unroll
            for (int d = 32; d >= 1; d >>= 1) {
              unsigned long long o = __shfl_down(v, d);
              if (o > v) v = o;
            }
            v = __shfl(v, 0);
            if (alive && myk == v) {
              int jj = 16383 - (int)(myk & 0x3FFFull);
              int slot = atomicAdd(&s_nsel, 1);
              srow[slot] = jj; selJ[slot] = jj;
              alive = false; myk = 0ull;
            }
          }
        }
      } else {
        for (int i = tid - 64; i < H_UNITS; i += 960)
          inhib[i] = __fmul_rn(inhib[i], 0.95f);
        for (int i = tid - 64; i < 2048; i += 960) fine[i] = 0u;
      }
      __syncthreads();  // B4

      // ---- phase E: +1 for selected, reset scalars ----
      if (tid < 64) {
        int j = selJ[tid];
        inhib[j] = __fadd_rn(inhib[j], 1.0f);
      } else if (tid == 64) {
        s_nsel = 0;
      } else if (tid == 65) {
        s_ccnt = 0;
      }
      __syncthreads();  // B5
    } else {
      // ------------------ FULL-ROW FALLBACK (validated path) ------------------
      fine[tid] = 0u; fine[1024 + tid] = 0u;
      histB[tid] = 0u; histB[1024 + tid] = 0u;
      if (tid == 0) { s_nsel = 0; s_ccnt = 0; }
      const float* erow = enc + (size_t)t * H_UNITS;
      unsigned int ok[QPT];
#pragma unroll
      for (int q = 0; q < QPT; ++q) {
        int j = q * 1024 + tid;
        float e = erow[j];
        float rr = __fmul_rn(fabsf(e), __fsub_rn(1.0f, inhib[j]));
        ok[q] = orderable(rr);
      }
      __syncthreads();
      unsigned int* hrep = ((tid >> 6) & 1) ? histB : fine;
#pragma unroll
      for (int q = 0; q < QPT; ++q) {
        int b = (int)(ok[q] >> 21);
        atomicAdd(&hrep[SWZ(b)], 1u);
      }
      __syncthreads();
      if (tid < 64) wave_find2048(fine, histB, 64u, tid, &s_b1, &s_above);
      __syncthreads();
      const unsigned int fb1 = (unsigned int)s_b1;
#pragma unroll
      for (int q = 0; q < QPT; ++q) {
        unsigned int o = ok[q];
        unsigned int bb = o >> 21;
        int j = q * 1024 + tid;
        if (bb > fb1) {
          int slot = atomicAdd(&s_nsel, 1);
          srow[slot] = j; selJ[slot] = j;
        } else if (bb == fb1) {
          int p = atomicAdd(&s_ccnt, 1);
          if (p < CAND_MAX)
            cand[p] = (((unsigned long long)o) << 14) | (unsigned long long)(16383 - j);
        }
      }
      __syncthreads();
      const int Cc0 = s_ccnt;
      if (Cc0 <= CAND_MAX) {
        if (tid < 64)
          wave_refine_pp(cand, hist128, Cc0, 64 - s_nsel, srow, selJ, &s_nsel, &s_wtmp);
      } else {
        // slow 3-pass (proven): 11+11+10-bit radix within bucket fb1
        int need2 = 64 - s_nsel;
        for (int i = tid; i < 2048; i += 1024) fine[i] = 0u;
        histB[tid] = 0u;
        if (tid == 0) s_tiecnt = 0;
        __syncthreads();
#pragma unroll
        for (int q = 0; q < QPT; ++q)
          if ((ok[q] >> 21) == fb1) atomicAdd(&fine[(ok[q] >> 10) & 0x7FFu], 1u);
        __syncthreads();
        suffix_find(fine, 32, need2, tid, &s_b2, &s_ab2);
        __syncthreads();
        const unsigned int pfx = (fb1 << 21) | ((unsigned int)s_b2 << 10);
        const int need3 = need2 - s_ab2;
#pragma unroll
        for (int q = 0; q < QPT; ++q)
          if ((ok[q] & 0xFFFFFC00u) == pfx) atomicAdd(&histB[ok[q] & 0x3FFu], 1u);
        __syncthreads();
        suffix_find(histB, 16, need3, tid, &s_b3, &s_ab3);
        __syncthreads();
        const unsigned int ostar = pfx | (unsigned int)s_b3;
        const int tneed = need3 - s_ab3;
        int* tl = (int*)cand;
#pragma unroll
        for (int q = 0; q < QPT; ++q) {
          unsigned int o = ok[q];
          int j = q * 1024 + tid;
          if (o > ostar && (o >> 21) == fb1) {
            int slot = atomicAdd(&s_nsel, 1);
            srow[slot] = j; selJ[slot] = j;
          } else if (o == ostar) {
            int p = atomicAdd(&s_tiecnt, 1);
            if (p < 1024) tl[p] = j;
          }
        }
        __syncthreads();
        if (tid == 0) {
          int tc = s_tiecnt; if (tc > 1024) tc = 1024;
          for (int k = 0; k < tneed; ++k) {
            int bi = 0x7FFFFFFF, bpos = 0;
            for (int i = 0; i < tc; ++i) {
              int v = tl[i];
              if (v < bi) { bi = v; bpos = i; }
            }
            tl[bpos] = 0x7FFFFFFF;
            selJ[64 - tneed + k] = bi;
            srow[64 - tneed + k] = bi;
          }
        }
      }
      __syncthreads();
      // decay + select + re-zero for next fast step
#pragma unroll
      for (int q = 0; q < QPT; ++q) {
        int j = q * 1024 + tid;
        inhib[j] = __fmul_rn(inhib[j], 0.95f);
      }
      __syncthreads();
      if (tid < 64) {
        int j = selJ[tid];
        inhib[j] = __fadd_rn(inhib[j], 1.0f);
      }
      fine[tid] = 0u; fine[1024 + tid] = 0u;
      if (tid == 64 + 1) s_ccnt = 0;
      if (tid == 64) s_nsel = 0;
      __syncthreads();
    }
  }
}

// ---------------------------------------------------------------------------
// Kernel 2-OLD (ws-gate fallback): validated full-row scan.
// ---------------------------------------------------------------------------
__global__ __launch_bounds__(1024) void scan_radix(const float* __restrict__ enc,
                                                   int* __restrict__ seli) {
  const int tid = threadIdx.x;
  __shared__ unsigned int histA[2048];
  __shared__ unsigned int histB[2048];
  __shared__ unsigned int hist128[128];
  __shared__ unsigned int bmap[2][512];
  __shared__ unsigned long long cand[4096];
  __shared__ int s_b1, s_nsel, s_ccnt, s_wtmp;
  __shared__ int s_b2, s_ab2, s_b3, s_ab3, s_tiecnt;
  __shared__ unsigned int s_abU;

  float iv[QPT];
  float ec[QPT];
#pragma unroll
  for (int q = 0; q < QPT; ++q) iv[q] = 0.0f;
#pragma unroll
  for (int q = 0; q < QPT; ++q) ec[q] = enc[q * 1024 + tid];

  for (int t = 0; t < B_ROWS; ++t) {
    const int cur = t & 1;
    unsigned int* bm = bmap[cur];
    int* srow = seli + t * 64;

    for (int i = tid; i < 2048; i += 1024) { histA[i] = 0u; histB[i] = 0u; }
    if (tid < 512) bm[tid] = 0u;
    if (tid == 0) { s_nsel = 0; s_ccnt = 0; }
    unsigned int ok[QPT];
#pragma unroll
    for (int q = 0; q < QPT; ++q) {
      float r = __fmul_rn(fabsf(ec[q]), __fsub_rn(1.0f, iv[q]));
      ok[q] = orderable(r);
    }
    __syncthreads();

    const int tn = (t + 1 < B_ROWS) ? (t + 1) : t;
    const float* nrow = enc + (size_t)tn * H_UNITS;
    float en[QPT];
#pragma unroll
    for (int q = 0; q < QPT; ++q) en[q] = nrow[q * 1024 + tid];

    unsigned int* hrep = ((tid >> 6) & 1) ? histB : histA;
#pragma unroll
    for (int q = 0; q < QPT; ++q) {
      int b = (int)(ok[q] >> 21);
      atomicAdd(&hrep[SWZ(b)], 1u);
    }
    __syncthreads();

    if (tid < 64) wave_find2048(histA, histB, 64u, tid, &s_b1, &s_abU);
    __syncthreads();

    const unsigned int b1 = (unsigned int)s_b1;
#pragma unroll
    for (int q = 0; q < QPT; ++q) {
      unsigned int o = ok[q];
      unsigned int bb = o >> 21;
      if (bb >= b1) {
        int j = q * 1024 + tid;
        if (bb > b1) {
          int slot = atomicAdd(&s_nsel, 1);
          srow[slot] = j;
          atomicOr(&bm[j >> 5], 1u << (j & 31));
        } else {
          int p = atomicAdd(&s_ccnt, 1);
          if (p < 2048)
            cand[p] = (((unsigned long long)o) << 14) | (unsigned long long)(16383 - j);
        }
      }
    }
    __syncthreads();

    const int Cc0 = s_ccnt;
    if (Cc0 <= 2048) {
      if (tid < 64) {
        int needc = 64 - s_nsel;
        int Cc = Cc0;
        int shift = 28;
        int rb = 0;
        while (true) {
          if (Cc <= needc) {
            for (int s = tid; s < Cc; s += 64) {
              unsigned long long k = cand[rb + s];
              int j = 16383 - (int)(k & 0x3FFFull);
              int slot = atomicAdd(&s_nsel, 1);
              srow[slot] = j;
              atomicOr(&bm[j >> 5], 1u << (j & 31));
            }
            break;
          }
          hist128[tid] = 0u;
          hist128[tid + 64] = 0u;
          if (tid == 0) s_wtmp = 0;
          asm volatile("s_waitcnt lgkmcnt(0)" ::: "memory");
          for (int s = tid; s < Cc; s += 64) {
            int ch = (int)((cand[rb + s] >> shift) & 127ull);
            atomicAdd(&hist128[ch], 1u);
          }
          asm volatile("s_waitcnt lgkmcnt(0)" ::: "memory");
          unsigned int c0 = hist128[2 * tid];
          unsigned int c1 = hist128[2 * tid + 1];
          unsigned int ps = c0 + c1;
#pragma unroll
          for (int d = 1; d < 64; d <<= 1) {
            unsigned int o = __shfl_down(ps, d);
            if (tid + d < 64) ps += o;
          }
          unsigned int incl = ps;
          unsigned int incln = __shfl_down(incl, 1);
          if (tid == 63) incln = 0u;
          unsigned int smid = incl - c0;
          bool crossHi = (smid >= (unsigned int)needc) && (incln < (unsigned int)needc);
          bool crossLo = (incl >= (unsigned int)needc) && (smid < (unsigned int)needc);
          unsigned long long bal = __ballot(crossHi || crossLo);
          int gl = __ffsll(bal) - 1;
          int hiF = __shfl((int)crossHi, gl);
          int vstar = 2 * gl + hiF;
          unsigned int aboveCh = (unsigned int)__shfl((int)(hiF ? incln : smid), gl);
          int wb = rb ^ 2048;
          for (int s = tid; s < Cc; s += 64) {
            unsigned long long k = cand[rb + s];
            int ch = (int)((k >> shift) & 127ull);
            if (ch > vstar) {
              int j = 16383 - (int)(k & 0x3FFFull);
              int slot = atomicAdd(&s_nsel, 1);
              srow[slot] = j;
              atomicOr(&bm[j >> 5], 1u << (j & 31));
            } else if (ch == vstar) {
              int p = atomicAdd(&s_wtmp, 1);
              cand[wb + p] = k;
            }
          }
          asm volatile("s_waitcnt lgkmcnt(0)" ::: "memory");
          needc -= (int)aboveCh;
          Cc = s_wtmp;
          rb = wb;
          shift = (shift >= 7) ? shift - 7 : 0;
        }
      }
    } else {
      int need2 = 64 - s_nsel;
      for (int i = tid; i < 2048; i += 1024) histA[i] = 0u;
      histB[tid] = 0u;
      if (tid == 0) s_tiecnt = 0;
      __syncthreads();
#pragma unroll
      for (int q = 0; q < QPT; ++q)
        if ((ok[q] >> 21) == b1) atomicAdd(&histA[(ok[q] >> 10) & 0x7FFu], 1u);
      __syncthreads();
      suffix_find(histA, 32, need2, tid, &s_b2, &s_ab2);
      __syncthreads();
      const unsigned int pfx = (b1 << 21) | ((unsigned int)s_b2 << 10);
      const int need3 = need2 - s_ab2;
#pragma unroll
      for (int q = 0; q < QPT; ++q)
        if ((ok[q] & 0xFFFFFC00u) == pfx) atomicAdd(&histB[ok[q] & 0x3FFu], 1u);
      __syncthreads();
      suffix_find(histB, 16, need3, tid, &s_b3, &s_ab3);
      __syncthreads();
      const unsigned int ostar = pfx | (unsigned int)s_b3;
      const int tneed = need3 - s_ab3;
      int* tl = (int*)cand;
#pragma unroll
      for (int q = 0; q < QPT; ++q) {
        unsigned int o = ok[q];
        int j = q * 1024 + tid;
        if (o > ostar && (o >> 21) == b1) {
          int slot = atomicAdd(&s_nsel, 1);
          srow[slot] = j;
          atomicOr(&bm[j >> 5], 1u << (j & 31));
        } else if (o == ostar) {
          int p = atomicAdd(&s_tiecnt, 1);
          if (p < 1024) tl[p] = j;
        }
      }
      __syncthreads();
      if (tid == 0) {
        int tc = s_tiecnt; if (tc > 1024) tc = 1024;
        for (int k = 0; k < tneed; ++k) {
          int bi = 0x7FFFFFFF, bpos = 0;
          for (int i = 0; i < tc; ++i) {
            int v = tl[i];
            if (v < bi) { bi = v; bpos = i; }
          }
          tl[bpos] = 0x7FFFFFFF;
          bmap[cur][bi >> 5] |= (1u << (bi & 31));
          srow[64 - tneed + k] = bi;
        }
      }
    }
    __syncthreads();

#pragma unroll
    for (int q = 0; q < QPT; ++q) {
      int j = q * 1024 + tid;
      float m = ((bm[j >> 5] >> (j & 31)) & 1u) ? 1.0f : 0.0f;
      iv[q] = __fadd_rn(__fmul_rn(iv[q], 0.95f), m);
      ec[q] = en[q];
    }
    __syncthreads();
  }
}

// ---------------------------------------------------------------------------
// Kernel 3: final top-64 over filtered = enc * mask, brute-force exact.
// (unchanged -- validated)
// ---------------------------------------------------------------------------
__global__ __launch_bounds__(1024) void final_brute(const int* __restrict__ seli,
                                                    float* __restrict__ out) {
  const int row = blockIdx.x;
  const int tid = threadIdx.x;
  __shared__ unsigned long long wmax[16];
  __shared__ unsigned long long s_win;
  __shared__ int wlist[64];
  __shared__ unsigned int bmap[512];
  const float* erow = out + (size_t)row * H_UNITS;

  if (tid < 512) bmap[tid] = 0u;
  __syncthreads();
  if (tid < 64) {
    int idx = seli[row * 64 + tid];
    atomicOr(&bmap[idx >> 5], 1u << (idx & 31));
  }
  __syncthreads();

  unsigned long long key[16];
  unsigned long long lmax = 0ull;
#pragma unroll
  for (int q = 0; q < 16; ++q) {
    int j = q * 1024 + tid;
    float e = erow[j];
    bool sel = (bmap[j >> 5] >> (j & 31)) & 1u;
    unsigned int eb = __float_as_uint(e);
    float f = __uint_as_float(sel ? eb : (eb & 0x80000000u));  // ±0 keeps sign
    unsigned long long k = make_key(f, j);
    key[q] = k;
    if (k > lmax) lmax = k;
  }
  __syncthreads();

  float4 z = make_float4(0.0f, 0.0f, 0.0f, 0.0f);
  float4* o4 = reinterpret_cast<float4*>(out + (size_t)row * H_UNITS);
  for (int i = tid; i < H_UNITS / 4; i += 1024) o4[i] = z;
  __syncthreads();

  for (int round = 0; round < 64; ++round) {
    unsigned long long v = lmax;
#pragma unroll
    for (int d = 32; d >= 1; d >>= 1) {
      unsigned long long o = __shfl_down(v, d);
      if (o > v) v = o;
    }
    if ((tid & 63) == 0) wmax[tid >> 6] = v;
    __syncthreads();
    if (tid == 0) {
      unsigned long long m = wmax[0];
#pragma unroll
      for (int w = 1; w < 16; ++w)
        if (wmax[w] > m) m = wmax[w];
      s_win = m;
      wlist[round] = 16383 - (int)(m & 0x3FFFull);
    }
    __syncthreads();
    unsigned long long Wk = s_win;
    if (lmax == Wk) {
      unsigned long long nm = 0ull;
#pragma unroll
      for (int q = 0; q < 16; ++q) {
        unsigned long long k = key[q];
        if (k < Wk && k > nm) nm = k;
      }
      lmax = nm;
    }
  }
  __syncthreads();
  if (tid < 64) out[(size_t)row * H_UNITS + wlist[tid]] = 1.0f;
}

// ---------------------------------------------------------------------------
extern "C" void kernel_launch(void* const* d_in, const int* in_sizes, int n_in,
                              void* d_out, int out_size, void* d_ws, size_t ws_size,
                              hipStream_t stream) {
  const float* inputs = (const float*)d_in[0];   // [512][2048] fp32
  const float* W = (const float*)d_in[1];        // [16384][2048] fp32
  float* out = (float*)d_out;                    // [512][16384] fp32 -- also enc scratch
  char* ws = (char*)d_ws;

  // ws layout: [0] seli 128KB | [131072] hdr 8KB (512*4 u32) | [139264] rec 8MB
  int* seli = (int*)(ws);
  unsigned int* hdr = (unsigned int*)(ws + 131072);
  unsigned long long* rec = (unsigned long long*)(ws + 139264);
  const size_t WS_NEEDED = 139264 + (size_t)B_ROWS * CAND_MAX * 8;  // 8,527,872

  float* enc = out;  // encoding scratch lives in d_out

  gemm_kernel<<<dim3(H_UNITS / 64, B_ROWS / 64), 256, 0, stream>>>(inputs, W, enc);
  if (ws_size >= WS_NEEDED) {
    precomp_cand<<<B_ROWS, 1024, 0, stream>>>(enc, rec, hdr);
    scan_cand<<<1, 1024, 0, stream>>>(enc, rec, hdr, seli);
  } else {
    scan_radix<<<1, 1024, 0, stream>>>(enc, seli);
  }
  final_brute<<<B_ROWS, 1024, 0, stream>>>(seli, out);
}